// Round 4
// baseline (5528.878 us; speedup 1.0000x reference)
//
#include <hip/hip_runtime.h>
#include <hip/hip_bf16.h>

#define NB 64      // batch
#define NT 512     // time
#define ND 512     // input dim
#define NH 768     // hidden
#define KTOT 1280  // ND + NH
#define NG 3072    // 4*NH

typedef short bf16x8 __attribute__((ext_vector_type(8)));
typedef float f32x4 __attribute__((ext_vector_type(4)));

__device__ __forceinline__ unsigned short f2b(float f) {
    unsigned int u; __builtin_memcpy(&u, &f, 4);
    u = u + 0x7FFFu + ((u >> 16) & 1u);   // round-to-nearest-even
    return (unsigned short)(u >> 16);
}
__device__ __forceinline__ float sigmoidf_(float x) { return 1.f / (1.f + __expf(-x)); }
__device__ __forceinline__ float tanhf_(float x) { return 2.f / (1.f + __expf(-2.f * x)) - 1.f; }

// -------- W transpose+convert: W[KTOT][NG] f32 -> WT[p][KTOT] bf16 --------
// Row order p encodes the consumer layout: logical col L = w*NH + hg*16 + r0
// lives at p = hg*64 + w*16 + r0  (so each hgroup's 64 cols are one contiguous slab).
__global__ __launch_bounds__(256) void transpose_w(const float* __restrict__ W,
                                                   unsigned short* __restrict__ WT) {
    __shared__ float tile[64][65];
    int bx = blockIdx.x % (NG / 64);   // col tile
    int by = blockIdx.x / (NG / 64);   // k tile
    int cb = bx * 64, kb = by * 64;
    int tid = threadIdx.x;
    {
        int r = tid >> 2;
        int coff = (tid & 3) * 16;
        const float* src = W + (size_t)(kb + r) * NG + cb + coff;
#pragma unroll
        for (int i = 0; i < 16; i += 4) {
            float4 v = *(const float4*)(src + i);
            tile[coff + i][r] = v.x; tile[coff + i + 1][r] = v.y;
            tile[coff + i + 2][r] = v.z; tile[coff + i + 3][r] = v.w;
        }
    }
    __syncthreads();
    {
        int c = tid >> 2;
        int koff = (tid & 3) * 16;
        bf16x8 o0, o1;
#pragma unroll
        for (int i = 0; i < 8; ++i) {
            o0[i] = (short)f2b(tile[c][koff + i]);
            o1[i] = (short)f2b(tile[c][koff + 8 + i]);
        }
        int L = cb + c;
        int w = L / NH;
        int rem = L - w * NH;
        int p = (rem >> 4) * 64 + w * 16 + (rem & 15);
        unsigned short* dst = WT + (size_t)p * KTOT + kb + koff;
        *(bf16x8*)dst       = o0;
        *(bf16x8*)(dst + 8) = o1;
    }
}

// -------- x f32 -> bf16 --------
__global__ __launch_bounds__(256) void convert_x(const float* __restrict__ src,
                                                 unsigned short* __restrict__ dst, int n8) {
    int i = blockIdx.x * 256 + threadIdx.x;
    if (i < n8) {
        const float4* s = (const float4*)(src + (size_t)i * 8);
        float4 v0 = s[0], v1 = s[1];
        bf16x8 o;
        o[0] = (short)f2b(v0.x); o[1] = (short)f2b(v0.y);
        o[2] = (short)f2b(v0.z); o[3] = (short)f2b(v0.w);
        o[4] = (short)f2b(v1.x); o[5] = (short)f2b(v1.y);
        o[6] = (short)f2b(v1.z); o[7] = (short)f2b(v1.w);
        *(bf16x8*)(dst + (size_t)i * 8) = o;
    }
}

// -------- Gx GEMM: Gx[dir][hg][b][t][64] = bf16(x[b,t,:]) @ Wx + bias (f32) --------
// grid: 2 dir x 48 hg x 64 b x 2 tchunk = 12288 blocks, 256 threads.
// Per block: M=256 (t rows), N=64 (this hg's col slab), K=512. Skips t >= seq_len[b].
__global__ __launch_bounds__(256) void gx_gemm(
    const unsigned short* __restrict__ xbf, const int* __restrict__ seq_len,
    const unsigned short* __restrict__ WT, const float* __restrict__ bias_fw,
    const float* __restrict__ bias_bw, float* __restrict__ Gx)
{
    __shared__ unsigned short As[256 * 136];   // 69,632 B; k-chunk=128, stride 136
    int bid = blockIdx.x;
    int dir = bid / (48 * 64 * 2);
    int rem = bid % (48 * 64 * 2);
    int hg = rem / 128;
    int r2 = rem % 128;
    int b  = r2 >> 1;
    int t0 = (r2 & 1) * 256;
    int L = seq_len[b];
    if (t0 >= L) return;

    int tid = threadIdx.x, lane = tid & 63, w = tid >> 6;
    int r0 = lane & 15, qq = lane >> 4, q8 = qq * 8;
    const float* bias = dir ? bias_bw : bias_fw;
    const unsigned short* Wd = WT + (size_t)dir * NG * KTOT;

    const unsigned short* Bp[4];
    float bv[4];
#pragma unroll
    for (int nf = 0; nf < 4; ++nf) {
        Bp[nf] = Wd + (size_t)(hg * 64 + nf * 16 + r0) * KTOT + q8;
        bv[nf] = bias[nf * NH + hg * 16 + r0];
    }
    f32x4 acc[4][4];
#pragma unroll
    for (int mf = 0; mf < 4; ++mf)
#pragma unroll
        for (int nf = 0; nf < 4; ++nf) {
            acc[mf][nf][0] = 0.f; acc[mf][nf][1] = 0.f;
            acc[mf][nf][2] = 0.f; acc[mf][nf][3] = 0.f;
        }

    const unsigned short* xbase = xbf + ((size_t)b * NT + t0) * ND;
    int srow = tid >> 3;
    int koff = (tid & 7) * 16;
    for (int kc = 0; kc < 4; ++kc) {
        int k0 = kc * 128;
        // stage A[256][128] (rows = t-offsets), 8 row-passes of 32 rows
#pragma unroll
        for (int p = 0; p < 8; ++p) {
            int row = srow + p * 32;
            const unsigned short* src = xbase + (size_t)row * ND + k0 + koff;
            unsigned short* dstp = &As[row * 136 + koff];
            *(bf16x8*)dstp       = *(const bf16x8*)src;
            *(bf16x8*)(dstp + 8) = *(const bf16x8*)(src + 8);
        }
        __syncthreads();
#pragma unroll
        for (int ki = 0; ki < 4; ++ki) {
            bf16x8 a[4], bq[4];
#pragma unroll
            for (int mf = 0; mf < 4; ++mf)
                a[mf] = *(const bf16x8*)&As[(w * 64 + mf * 16 + r0) * 136 + ki * 32 + q8];
#pragma unroll
            for (int nf = 0; nf < 4; ++nf)
                bq[nf] = *(const bf16x8*)(Bp[nf] + k0 + ki * 32);
#pragma unroll
            for (int mf = 0; mf < 4; ++mf)
#pragma unroll
                for (int nf = 0; nf < 4; ++nf)
                    acc[mf][nf] = __builtin_amdgcn_mfma_f32_16x16x32_bf16(a[mf], bq[nf], acc[mf][nf], 0, 0, 0);
        }
        __syncthreads();
    }
    // epilogue: C row = t-offset (w*64+mf*16+qq*4+r), col = nf*16+r0; masked t<L
    float* gxb = Gx + (((size_t)(dir * 48 + hg) * NB + b) * NT + t0) * 64;
#pragma unroll
    for (int mf = 0; mf < 4; ++mf) {
#pragma unroll
        for (int r = 0; r < 4; ++r) {
            int trow = w * 64 + mf * 16 + qq * 4 + r;
            if (t0 + trow < L) {
                float* orow = gxb + (size_t)trow * 64 + r0;
                orow[0]  = acc[mf][0][r] + bv[0];
                orow[16] = acc[mf][1][r] + bv[1];
                orow[32] = acc[mf][2][r] + bv[2];
                orow[48] = acc[mf][3][r] + bv[3];
            }
        }
    }
}

// ---------------- lean persistent recurrent kernel (Gx path) ----------------
// 192 blocks = dir(2) x bgroup(2) x hgroup(48); 256 threads; 1 block/CU (149KB LDS)
__global__ __launch_bounds__(256) void lstm_recur(
    const int* __restrict__ seq_len,
    const unsigned short* __restrict__ WT,       // permuted [2][3072][KTOT] bf16
    const float* __restrict__ Gx,                // [2][48][NB][NT][64] f32 (bias baked)
    unsigned short* __restrict__ hbufs,          // [3][2][NB][NH] bf16
    float* __restrict__ h_final,                 // [2][NB][NH] f32
    float* __restrict__ out,                     // [NB][NT][2*NH] f32
    unsigned int* __restrict__ barrier_cnts)
{
    extern __shared__ char smem[];
    unsigned short* Wh = (unsigned short*)smem;               // [64][776]
    unsigned short* A  = (unsigned short*)(smem + 64 * 776 * 2); // [32][776] h staging
    float* gl = (float*)(smem + 64 * 776 * 2);                // overlay: [4][32] rows, stride 17

    int bid = blockIdx.x;
    int hg = bid % 48;
    int bgroup = (bid / 48) & 1;
    int dir = bid / 96;
    int grp = bid / 48;
    int b0 = bgroup * 32;
    int hbase = hg * 16;
    int tid = threadIdx.x;
    int lane = tid & 63;
    int wave = tid >> 6;                         // = gate index

    const unsigned short* Wd = WT + (size_t)dir * NG * KTOT;

    // ---- Wh fill: contiguous 64-row slab [hg*64, hg*64+64), h-part k>=ND ----
    {
        int rl = tid >> 2;                       // 0..63
        const unsigned short* src = Wd + (size_t)(hg * 64 + rl) * KTOT + ND;
        unsigned short* dstrow = Wh + rl * 776;
#pragma unroll
        for (int i = 0; i < 24; ++i) {
            int off = (tid & 3) * 8 + i * 32;
            *(bf16x8*)(dstrow + off) = *(const bf16x8*)(src + off);
        }
    }

    // ---- per-thread constants ----
    int srow = tid >> 3;
    int koff0 = (tid & 7) * 8;
    int r0 = lane & 15;
    int q8 = (lane >> 4) * 8;
    int qq = lane >> 4;
    const unsigned short* WhB = Wh + (size_t)(wave * 16 + r0) * 776 + q8;

    int ebl0 = tid >> 4;                         // 0..15
    int ehl = tid & 15;
    int hidx = hbase + ehl;
    int Lb[2]; Lb[0] = seq_len[b0 + ebl0]; Lb[1] = seq_len[b0 + ebl0 + 16];
    float c_reg[2] = {0.f, 0.f};
    unsigned short h_reg[2] = {0, 0};

    int Lmax = 1;
    for (int i = 0; i < 32; ++i) { int l = seq_len[b0 + i]; Lmax = l > Lmax ? l : Lmax; }

    const float* gxg = Gx + ((size_t)(dir * 48 + hg) * NB) * NT * 64;
    unsigned int* cnt = barrier_cnts + grp * 64;

    for (int step = 0; step < Lmax; ++step) {
        const unsigned short* hin = hbufs + (size_t)(step % 3) * (2 * NB * NH) + (size_t)dir * NB * NH;
        unsigned short* hout      = hbufs + (size_t)((step + 1) % 3) * (2 * NB * NH) + (size_t)dir * NB * NH;

        // ---- Gx prefetch (no h dependency; overlaps h staging) ----
        float gxv[2][4];
        int te[2];
#pragma unroll
        for (int it = 0; it < 2; ++it) {
            int bb = b0 + ebl0 + it * 16;
            int t = dir ? (Lb[it] - 1 - step) : step;
            if (t < 0) t = 0;
            te[it] = t;
            const float* g = gxg + ((size_t)bb * NT + t) * 64 + ehl;
#pragma unroll
            for (int gg = 0; gg < 4; ++gg) gxv[it][gg] = g[gg * 16];
        }

        // ---- stage h into A ----
        {
            const unsigned short* hr = hin + (size_t)(b0 + srow) * NH;
#pragma unroll
            for (int i = 0; i < 12; ++i) {
                int kl = koff0 + i * 64;
                *(bf16x8*)&A[srow * 776 + kl] = *(const bf16x8*)(hr + kl);
            }
        }
        __syncthreads();

        f32x4 acc0, acc1;
        acc0[0] = acc0[1] = acc0[2] = acc0[3] = 0.f;
        acc1 = acc0;
#pragma unroll
        for (int ks = 0; ks < 24; ++ks) {
            bf16x8 a0 = *(const bf16x8*)&A[r0 * 776 + ks * 32 + q8];
            bf16x8 a1 = *(const bf16x8*)&A[(r0 + 16) * 776 + ks * 32 + q8];
            bf16x8 bf = *(const bf16x8*)(WhB + ks * 32);
            acc0 = __builtin_amdgcn_mfma_f32_16x16x32_bf16(a0, bf, acc0, 0, 0, 0);
            acc1 = __builtin_amdgcn_mfma_f32_16x16x32_bf16(a1, bf, acc1, 0, 0, 0);
        }
        __syncthreads();                          // A consumed; gl overlay safe

        // C/D: col = lane&15, row = qq*4 + reg; gl row stride 17 (conflict pad)
#pragma unroll
        for (int r = 0; r < 4; ++r) {
            gl[(wave * 32 + qq * 4 + r) * 17 + r0] = acc0[r];
            gl[(wave * 32 + 16 + qq * 4 + r) * 17 + r0] = acc1[r];
        }
        __syncthreads();

        // ---- epilogue: cell update ----
#pragma unroll
        for (int it = 0; it < 2; ++it) {
            int bl = ebl0 + it * 16;
            int bb = b0 + bl;
            if (step < Lb[it]) {
                float gi = gl[(0 * 32 + bl) * 17 + ehl] + gxv[it][0];
                float gj = gl[(1 * 32 + bl) * 17 + ehl] + gxv[it][1];
                float gf = gl[(2 * 32 + bl) * 17 + ehl] + gxv[it][2];
                float go = gl[(3 * 32 + bl) * 17 + ehl] + gxv[it][3];
                float nc = c_reg[it] * sigmoidf_(gf + 1.f) + sigmoidf_(gi) * tanhf_(gj);
                float nh = tanhf_(nc) * sigmoidf_(go);
                c_reg[it] = nc;
                h_reg[it] = f2b(nh);
                if (step == Lb[it] - 1)
                    h_final[((size_t)dir * NB + bb) * NH + hidx] = nh;
                int t_out = dir ? te[it] : step;
                out[((size_t)bb * NT + t_out) * (2 * NH) + dir * NH + hidx] = nh;
                hout[(size_t)bb * NH + hidx] = h_reg[it];
            }
        }

        // ---- group barrier (48 blocks sharing this dir+bgroup h state) ----
        __syncthreads();
        if (tid == 0) {
            __hip_atomic_fetch_add(cnt, 1u, __ATOMIC_RELEASE, __HIP_MEMORY_SCOPE_AGENT);
            unsigned int tgt = 48u * (unsigned)(step + 1);
            while (__hip_atomic_load(cnt, __ATOMIC_RELAXED, __HIP_MEMORY_SCOPE_AGENT) < tgt)
                __builtin_amdgcn_s_sleep(2);
            (void)__hip_atomic_load(cnt, __ATOMIC_ACQUIRE, __HIP_MEMORY_SCOPE_AGENT);
        }
        __syncthreads();
    }
}

// ---------------- fallback: round-3 persistent kernel (adapted to permuted WT) ----------------
__global__ __launch_bounds__(256) void lstm_persistent(
    const float* __restrict__ seq, const unsigned short* __restrict__ xbf, int use_xbf,
    const int* __restrict__ seq_len, const unsigned short* __restrict__ WT,
    const float* __restrict__ bias_fw, const float* __restrict__ bias_bw,
    unsigned short* __restrict__ hbufs, float* __restrict__ h_final,
    float* __restrict__ out, unsigned int* __restrict__ barrier_cnts)
{
    extern __shared__ char smem[];
    unsigned short* Wh = (unsigned short*)smem;
    unsigned short* A  = (unsigned short*)(smem + 64 * 776 * 2);
    float* gl = (float*)(smem + 64 * 776 * 2);

    int bid = blockIdx.x;
    int hg = bid % 48;
    int bgroup = (bid / 48) & 1;
    int dir = bid / 96;
    int grp = bid / 48;
    int b0 = bgroup * 32;
    int hbase = hg * 16;
    int tid = threadIdx.x;
    int lane = tid & 63;
    int wave = tid >> 6;

    const unsigned short* Wd = WT + (size_t)dir * NG * KTOT;
    const float* bias = dir ? bias_bw : bias_fw;

    {
        int rl = tid >> 2;
        const unsigned short* src = Wd + (size_t)(hg * 64 + rl) * KTOT + ND;
        unsigned short* dstrow = Wh + rl * 776;
#pragma unroll
        for (int i = 0; i < 24; ++i) {
            int off = (tid & 3) * 8 + i * 32;
            *(bf16x8*)(dstrow + off) = *(const bf16x8*)(src + off);
        }
    }

    int srow = tid >> 3;
    int sb = b0 + srow;
    int Ls = seq_len[sb];
    int koff0 = (tid & 7) * 8;
    const float* xrow_f = seq + (size_t)sb * NT * ND;
    const unsigned short* xrow_b = use_xbf ? (xbf + (size_t)sb * NT * ND) : (const unsigned short*)0;

    int r0 = lane & 15;
    int q8 = (lane >> 4) * 8;
    int qq = lane >> 4;
    const unsigned short* BpX = Wd + (size_t)(hg * 64 + wave * 16 + r0) * KTOT + q8;
    const unsigned short* WhB = Wh + (size_t)(wave * 16 + r0) * 776 + q8;
    float bv = bias[wave * NH + hbase + r0];

    int ebl0 = tid >> 4;
    int ehl = tid & 15;
    int hidx = hbase + ehl;
    int Lb[2]; Lb[0] = seq_len[b0 + ebl0]; Lb[1] = seq_len[b0 + ebl0 + 16];
    float c_reg[2] = {0.f, 0.f};
    unsigned short h_reg[2] = {0, 0};

    unsigned int* cnt = barrier_cnts + grp * 64;

    for (int step = 0; step < NT; ++step) {
        const unsigned short* hin = hbufs + (size_t)(step % 3) * (2 * NB * NH) + (size_t)dir * NB * NH;
        unsigned short* hout      = hbufs + (size_t)((step + 1) % 3) * (2 * NB * NH) + (size_t)dir * NB * NH;
        int t_in = dir ? (Ls - 1 - step) : step;
        if (t_in < 0) t_in = 0;

        if (use_xbf) {
            const unsigned short* xr = xrow_b + (size_t)t_in * ND;
#pragma unroll
            for (int i = 0; i < 8; ++i) {
                int kl = koff0 + i * 64;
                *(bf16x8*)&A[srow * 776 + kl] = *(const bf16x8*)(xr + kl);
            }
        } else {
            const float* xr = xrow_f + (size_t)t_in * ND;
#pragma unroll
            for (int i = 0; i < 8; ++i) {
                int kl = koff0 + i * 64;
                float4 v0 = *(const float4*)(xr + kl);
                float4 v1 = *(const float4*)(xr + kl + 4);
                bf16x8 o;
                o[0] = (short)f2b(v0.x); o[1] = (short)f2b(v0.y);
                o[2] = (short)f2b(v0.z); o[3] = (short)f2b(v0.w);
                o[4] = (short)f2b(v1.x); o[5] = (short)f2b(v1.y);
                o[6] = (short)f2b(v1.z); o[7] = (short)f2b(v1.w);
                *(bf16x8*)&A[srow * 776 + kl] = o;
            }
        }
        __syncthreads();

        f32x4 acc0; acc0[0] = bv; acc0[1] = bv; acc0[2] = bv; acc0[3] = bv;
        f32x4 acc1 = acc0;
#pragma unroll
        for (int ks = 0; ks < 16; ++ks) {
            bf16x8 a0 = *(const bf16x8*)&A[r0 * 776 + ks * 32 + q8];
            bf16x8 a1 = *(const bf16x8*)&A[(r0 + 16) * 776 + ks * 32 + q8];
            bf16x8 bf = *(const bf16x8*)(BpX + ks * 32);
            acc0 = __builtin_amdgcn_mfma_f32_16x16x32_bf16(a0, bf, acc0, 0, 0, 0);
            acc1 = __builtin_amdgcn_mfma_f32_16x16x32_bf16(a1, bf, acc1, 0, 0, 0);
        }
        __syncthreads();

        {
            const unsigned short* hr = hin + (size_t)sb * NH;
#pragma unroll
            for (int i = 0; i < 12; ++i) {
                int kl = koff0 + i * 64;
                *(bf16x8*)&A[srow * 776 + kl] = *(const bf16x8*)(hr + kl);
            }
        }
        __syncthreads();
#pragma unroll
        for (int ks = 0; ks < 24; ++ks) {
            bf16x8 a0 = *(const bf16x8*)&A[r0 * 776 + ks * 32 + q8];
            bf16x8 a1 = *(const bf16x8*)&A[(r0 + 16) * 776 + ks * 32 + q8];
            bf16x8 bf = *(const bf16x8*)(WhB + ks * 32);
            acc0 = __builtin_amdgcn_mfma_f32_16x16x32_bf16(a0, bf, acc0, 0, 0, 0);
            acc1 = __builtin_amdgcn_mfma_f32_16x16x32_bf16(a1, bf, acc1, 0, 0, 0);
        }
        __syncthreads();

#pragma unroll
        for (int r = 0; r < 4; ++r) {
            gl[(wave * 32 + qq * 4 + r) * 17 + r0] = acc0[r];
            gl[(wave * 32 + 16 + qq * 4 + r) * 17 + r0] = acc1[r];
        }
        __syncthreads();

#pragma unroll
        for (int it = 0; it < 2; ++it) {
            int bl = ebl0 + it * 16;
            int bb = b0 + bl;
            unsigned short hv = h_reg[it];
            if (step < Lb[it]) {
                float gi = gl[(0 * 32 + bl) * 17 + ehl];
                float gj = gl[(1 * 32 + bl) * 17 + ehl];
                float gf = gl[(2 * 32 + bl) * 17 + ehl];
                float go = gl[(3 * 32 + bl) * 17 + ehl];
                float nc = c_reg[it] * sigmoidf_(gf + 1.f) + sigmoidf_(gi) * tanhf_(gj);
                float nh = tanhf_(nc) * sigmoidf_(go);
                c_reg[it] = nc;
                hv = f2b(nh);
                h_reg[it] = hv;
                if (step == Lb[it] - 1)
                    h_final[((size_t)dir * NB + bb) * NH + hidx] = nh;
                int t_out = dir ? (Lb[it] - 1 - step) : step;
                out[((size_t)bb * NT + t_out) * (2 * NH) + dir * NH + hidx] = nh;
            }
            hout[(size_t)bb * NH + hidx] = hv;
        }

        __syncthreads();
        if (tid == 0) {
            __hip_atomic_fetch_add(cnt, 1u, __ATOMIC_RELEASE, __HIP_MEMORY_SCOPE_AGENT);
            unsigned int tgt = 48u * (unsigned)(step + 1);
            while (__hip_atomic_load(cnt, __ATOMIC_RELAXED, __HIP_MEMORY_SCOPE_AGENT) < tgt)
                __builtin_amdgcn_s_sleep(2);
            (void)__hip_atomic_load(cnt, __ATOMIC_ACQUIRE, __HIP_MEMORY_SCOPE_AGENT);
        }
        __syncthreads();
    }
}

// ---------------- final hidden state (f32) -> d_out tail ----------------
__global__ __launch_bounds__(256) void write_state(const float* __restrict__ h_final,
                                                   float* __restrict__ out_state) {
    int i = blockIdx.x * 256 + threadIdx.x;
    if (i < 2 * NB * NH) {
        int dir = i / (NB * NH);
        int rem = i - dir * (NB * NH);
        int b = rem / NH, h = rem - (rem / NH) * NH;
        out_state[(size_t)b * (2 * NH) + dir * NH + h] = h_final[i];
    }
}

extern "C" void kernel_launch(void* const* d_in, const int* in_sizes, int n_in,
                              void* d_out, int out_size, void* d_ws, size_t ws_size,
                              hipStream_t stream) {
    const float* seq   = (const float*)d_in[0];
    const int* seq_len = (const int*)d_in[1];
    const float* W_fw  = (const float*)d_in[2];
    const float* b_fw  = (const float*)d_in[3];
    const float* W_bw  = (const float*)d_in[4];
    const float* b_bw  = (const float*)d_in[5];
    float* out = (float*)d_out;

    char* ws = (char*)d_ws;
    size_t off = 0;
    unsigned short* WT = (unsigned short*)(ws + off);  off += (size_t)2 * NG * KTOT * 2;   // 15.7 MB
    unsigned short* hbufs = (unsigned short*)(ws + off);
    size_t hbuf_bytes = (size_t)3 * 2 * NB * NH * 2;   off += hbuf_bytes;
    float* h_final = (float*)(ws + off);
    size_t hf_bytes = (size_t)2 * NB * NH * 4;         off += hf_bytes;
    unsigned int* barrier_cnts = (unsigned int*)(ws + off);
    size_t bar_bytes = 1024;                           off += bar_bytes;
    unsigned short* xbf = (unsigned short*)(ws + off);
    size_t xbf_bytes = (size_t)NB * NT * ND * 2;       // 33.5 MB
    size_t need_xbf = off + xbf_bytes;
    float* Gx = (float*)(ws + need_xbf);
    size_t gx_bytes = (size_t)2 * 48 * NB * NT * 64 * 4;  // 805 MB
    size_t need_full = need_xbf + gx_bytes;
    int use_xbf = (ws_size >= need_xbf) ? 1 : 0;
    int use_gx  = (ws_size >= need_full) ? 1 : 0;

    hipMemsetAsync(out, 0, (size_t)out_size * sizeof(float), stream);
    hipMemsetAsync(hbufs, 0, hbuf_bytes + hf_bytes + bar_bytes, stream);

    transpose_w<<<(KTOT / 64) * (NG / 64), 256, 0, stream>>>(W_fw, WT);
    transpose_w<<<(KTOT / 64) * (NG / 64), 256, 0, stream>>>(W_bw, WT + (size_t)NG * KTOT);
    if (use_xbf) {
        int n8 = NB * NT * ND / 8;
        convert_x<<<(n8 + 255) / 256, 256, 0, stream>>>(seq, xbf, n8);
    }

    size_t smem_bytes = (size_t)64 * 776 * 2 + (size_t)32 * 776 * 2;   // 148,992
    if (use_gx) {
        gx_gemm<<<2 * 48 * 64 * 2, 256, 0, stream>>>(xbf, seq_len, WT, b_fw, b_bw, Gx);
        lstm_recur<<<192, 256, smem_bytes, stream>>>(
            seq_len, WT, Gx, hbufs, h_final, out, barrier_cnts);
    } else {
        lstm_persistent<<<192, 256, smem_bytes, stream>>>(
            seq, xbf, use_xbf, seq_len, WT, b_fw, b_bw,
            hbufs, h_final, out, barrier_cnts);
    }

    write_state<<<(2 * NB * NH + 255) / 256, 256, 0, stream>>>(
        h_final, out + (size_t)NB * NT * 2 * NH);
}